// Round 1
// baseline (224.365 us; speedup 1.0000x reference)
//
#include <hip/hip_runtime.h>
#include <hip/hip_bf16.h>
#include <stdint.h>

// Problem shape (fixed by reference): B=2, S=1024 -> M=2048; N=4096; K=4096
#define M_DIM 2048
#define N_DIM 4096
#define K_DIM 4096

#define BM 128
#define BN 128
#define BK 32

typedef __attribute__((ext_vector_type(8))) short  short8;
typedef __attribute__((ext_vector_type(8))) __bf16 bf16x8;
typedef __attribute__((ext_vector_type(4))) float  f32x4;

// ---------- helpers ----------

// RNE float -> bf16 bits (inputs are finite normals; NaN path not needed)
__device__ __forceinline__ ushort f2bf(float f) {
    uint32_t u = __float_as_uint(f);
    u += 0x7fffu + ((u >> 16) & 1u);
    return (ushort)(u >> 16);
}

__device__ __forceinline__ void load_lds16(const void* g, void* l) {
    __builtin_amdgcn_global_load_lds(
        (const __attribute__((address_space(1))) void*)g,
        (__attribute__((address_space(3))) void*)l,
        16, 0, 0);
}

// ---------- conversion kernels ----------

union Pack8 { ushort u[8]; uint4 v; };

// x: fp32 -> bf16, 8 elems/thread
__global__ __launch_bounds__(256) void cvt_x_kernel(const float* __restrict__ x,
                                                    ushort* __restrict__ o) {
    size_t i = ((size_t)blockIdx.x * 256 + threadIdx.x) * 8;
    float4 a = *(const float4*)(x + i);
    float4 b = *(const float4*)(x + i + 4);
    Pack8 t;
    t.u[0] = f2bf(a.x); t.u[1] = f2bf(a.y); t.u[2] = f2bf(a.z); t.u[3] = f2bf(a.w);
    t.u[4] = f2bf(b.x); t.u[5] = f2bf(b.y); t.u[6] = f2bf(b.z); t.u[7] = f2bf(b.w);
    *(uint4*)(o + i) = t.v;
}

// weight: int32 (values in [-128,127]) -> bf16 (exact), 8 elems/thread
__global__ __launch_bounds__(256) void cvt_w_kernel(const int* __restrict__ w,
                                                    ushort* __restrict__ o) {
    size_t i = ((size_t)blockIdx.x * 256 + threadIdx.x) * 8;
    int4 a = *(const int4*)(w + i);
    int4 b = *(const int4*)(w + i + 4);
    Pack8 t;
    t.u[0] = f2bf((float)a.x); t.u[1] = f2bf((float)a.y);
    t.u[2] = f2bf((float)a.z); t.u[3] = f2bf((float)a.w);
    t.u[4] = f2bf((float)b.x); t.u[5] = f2bf((float)b.y);
    t.u[6] = f2bf((float)b.z); t.u[7] = f2bf((float)b.w);
    *(uint4*)(o + i) = t.v;
}

// ---------- GEMM: C[m][n] = sum_k A[m][k]*B[n][k]; epilogue *scales[n]+bias[n] ----------
// m97 structure: 128x128 tile, BK=32, 4 waves 2x2, 4x4 16x16x32 MFMA tiles per wave,
// global_load_lds width=16 staging, unpadded 128x32 LDS (required by lds-DMA layout).

__global__ __launch_bounds__(256) void gemm_bt_bf16(
    const ushort* __restrict__ A,      // [M,K] bf16 bits
    const ushort* __restrict__ B,      // [N,K] bf16 bits
    const float*  __restrict__ scales, // [N]
    const float*  __restrict__ bias,   // [N]
    float* __restrict__ C)             // [M,N]
{
    __shared__ __align__(16) ushort As[BM * BK];  // 8 KiB
    __shared__ __align__(16) ushort Bs[BN * BK];  // 8 KiB

    const int tid  = threadIdx.x;
    const int bm   = blockIdx.y;
    const int bn   = blockIdx.x;
    const int lane = tid & 63;
    const int wave = tid >> 6;
    const int wm   = (wave >> 1) * 64;   // wave row offset in tile
    const int wn   = (wave & 1) * 64;    // wave col offset in tile
    const int l16  = lane & 15;
    const int quad = lane >> 4;

    // Staging: 256 threads x 16B = 4 KiB/instr; 2 instrs per 8 KiB tile.
    // thread t covers tile byte offset t*16 (+4096 for second instr):
    // row = t/4, k-elems = (t%4)*8. Wave-uniform-base + lane*16 holds.
    const int trow = tid >> 2;          // 0..63
    const int tcol = (tid & 3) * 8;     // element offset in K within tile

    const ushort* ga0 = A + (size_t)(bm * BM + trow)      * K_DIM + tcol;
    const ushort* ga1 = A + (size_t)(bm * BM + 64 + trow) * K_DIM + tcol;
    const ushort* gb0 = B + (size_t)(bn * BN + trow)      * K_DIM + tcol;
    const ushort* gb1 = B + (size_t)(bn * BN + 64 + trow) * K_DIM + tcol;
    ushort* la0 = As + trow * BK + tcol;
    ushort* la1 = As + (64 + trow) * BK + tcol;
    ushort* lb0 = Bs + trow * BK + tcol;
    ushort* lb1 = Bs + (64 + trow) * BK + tcol;

    f32x4 acc[4][4] = {};

    for (int k0 = 0; k0 < K_DIM; k0 += BK) {
        __syncthreads();               // prev compute done before overwrite
        load_lds16(ga0 + k0, la0);
        load_lds16(ga1 + k0, la1);
        load_lds16(gb0 + k0, lb0);
        load_lds16(gb1 + k0, lb1);
        __syncthreads();               // drains vmcnt for lds-DMA

        short8 af[4], bf[4];
#pragma unroll
        for (int i = 0; i < 4; i++)
            af[i] = *(const short8*)(As + (wm + i * 16 + l16) * BK + quad * 8);
#pragma unroll
        for (int j = 0; j < 4; j++)
            bf[j] = *(const short8*)(Bs + (wn + j * 16 + l16) * BK + quad * 8);

#pragma unroll
        for (int i = 0; i < 4; i++)
#pragma unroll
            for (int j = 0; j < 4; j++)
                acc[i][j] = __builtin_amdgcn_mfma_f32_16x16x32_bf16(
                    __builtin_bit_cast(bf16x8, af[i]),
                    __builtin_bit_cast(bf16x8, bf[j]),
                    acc[i][j], 0, 0, 0);
    }

    // Epilogue. C/D layout (verified m89): col = lane&15, row = quad*4 + reg.
#pragma unroll
    for (int j = 0; j < 4; j++) {
        const int col = bn * BN + wn + j * 16 + l16;
        const float s = scales[col];
        const float b = bias[col];
#pragma unroll
        for (int i = 0; i < 4; i++) {
            const int row0 = bm * BM + wm + i * 16 + quad * 4;
#pragma unroll
            for (int r = 0; r < 4; r++) {
                C[(size_t)(row0 + r) * N_DIM + col] = acc[i][j][r] * s + b;
            }
        }
    }
}

// ---------- launch ----------

extern "C" void kernel_launch(void* const* d_in, const int* in_sizes, int n_in,
                              void* d_out, int out_size, void* d_ws, size_t ws_size,
                              hipStream_t stream) {
    const float* x      = (const float*)d_in[0];   // [2,1024,4096] fp32
    const int*   w      = (const int*)d_in[1];     // [4096,4096] int (values in [-128,127])
    const float* scales = (const float*)d_in[2];   // [4096]
    const float* bias   = (const float*)d_in[3];   // [4096]
    float*       out    = (float*)d_out;           // [2,1024,4096] fp32

    // workspace layout: A_bf16 [M*K] then B_bf16 [N*K]
    ushort* Abf = (ushort*)d_ws;                                   // 16 MiB
    ushort* Bbf = (ushort*)((char*)d_ws + (size_t)M_DIM * K_DIM * 2); // 32 MiB

    cvt_x_kernel<<<(M_DIM * (size_t)K_DIM) / 8 / 256, 256, 0, stream>>>(x, Abf);
    cvt_w_kernel<<<((size_t)N_DIM * K_DIM) / 8 / 256, 256, 0, stream>>>(w, Bbf);

    dim3 grid(N_DIM / BN, M_DIM / BM);  // (32, 16) = 512 blocks
    gemm_bt_bf16<<<grid, 256, 0, stream>>>(Abf, Bbf, scales, bias, out);
}

// Round 2
// 200.319 us; speedup vs baseline: 1.1200x; 1.1200x over previous
//
#include <hip/hip_runtime.h>
#include <hip/hip_bf16.h>
#include <stdint.h>

// Shape fixed by reference: B=2, S=1024 -> M=2048; N=4096; K=4096
#define M_DIM 2048
#define N_DIM 4096
#define K_DIM 4096

#define BM 128
#define BN 128
#define BK 64   // 64 K-iters; 32 KiB LDS; 16 MFMA/wave/iter

typedef __attribute__((ext_vector_type(8))) short  short8;
typedef __attribute__((ext_vector_type(8))) __bf16 bf16x8;
typedef __attribute__((ext_vector_type(4))) float  f32x4;

// RNE float -> bf16 bits
__device__ __forceinline__ ushort f2bf(float f) {
    uint32_t u = __float_as_uint(f);
    u += 0x7fffu + ((u >> 16) & 1u);
    return (ushort)(u >> 16);
}

__device__ __forceinline__ void load_lds16(const void* g, void* l) {
    __builtin_amdgcn_global_load_lds(
        (const __attribute__((address_space(1))) void*)g,
        (__attribute__((address_space(3))) void*)l,
        16, 0, 0);
}

// ---------- fused conversion: one dispatch for x(fp32->bf16) and w(int->bf16) ----------
union Pack8 { ushort u[8]; uint4 v; };

#define XBLK ((M_DIM * (size_t)K_DIM) / 8 / 256)   // 4096 blocks, 8 elem/thread
#define WBLK (((size_t)N_DIM * K_DIM) / 16 / 256)  // 4096 blocks, 16 elem/thread

__global__ __launch_bounds__(256) void cvt_fused(const float* __restrict__ x,
                                                 const int* __restrict__ w,
                                                 ushort* __restrict__ Ab,
                                                 ushort* __restrict__ Bb) {
    const int b = blockIdx.x;
    if (b < (int)XBLK) {
        size_t i = ((size_t)b * 256 + threadIdx.x) * 8;
        float4 a = *(const float4*)(x + i);
        float4 c = *(const float4*)(x + i + 4);
        Pack8 t;
        t.u[0] = f2bf(a.x); t.u[1] = f2bf(a.y); t.u[2] = f2bf(a.z); t.u[3] = f2bf(a.w);
        t.u[4] = f2bf(c.x); t.u[5] = f2bf(c.y); t.u[6] = f2bf(c.z); t.u[7] = f2bf(c.w);
        *(uint4*)(Ab + i) = t.v;
    } else {
        size_t i = ((size_t)(b - (int)XBLK) * 256 + threadIdx.x) * 16;
        int4 a0 = *(const int4*)(w + i);
        int4 a1 = *(const int4*)(w + i + 4);
        int4 a2 = *(const int4*)(w + i + 8);
        int4 a3 = *(const int4*)(w + i + 12);
        Pack8 t0, t1;
        t0.u[0] = f2bf((float)a0.x); t0.u[1] = f2bf((float)a0.y);
        t0.u[2] = f2bf((float)a0.z); t0.u[3] = f2bf((float)a0.w);
        t0.u[4] = f2bf((float)a1.x); t0.u[5] = f2bf((float)a1.y);
        t0.u[6] = f2bf((float)a1.z); t0.u[7] = f2bf((float)a1.w);
        t1.u[0] = f2bf((float)a2.x); t1.u[1] = f2bf((float)a2.y);
        t1.u[2] = f2bf((float)a2.z); t1.u[3] = f2bf((float)a2.w);
        t1.u[4] = f2bf((float)a3.x); t1.u[5] = f2bf((float)a3.y);
        t1.u[6] = f2bf((float)a3.z); t1.u[7] = f2bf((float)a3.w);
        *(uint4*)(Bb + i)     = t0.v;
        *(uint4*)(Bb + i + 8) = t1.v;
    }
}

// ---------- GEMM: C = A(bf16)[M,K] x B(bf16)[N,K]^T, epilogue *scales[n]+bias[n] ----------
// 512 threads = 8 waves in 2x4; each wave owns 64x32 (acc[4][2] of 16x16).
// BK=64, glds width=16 staging, XOR-swizzled LDS columns (cg_phys = cg_log ^ (row&7))
// applied on the GLOBAL source address (glds LDS dest is fixed at base+lane*16).

__global__ __launch_bounds__(512, 4) void gemm_bt_bf16(
    const ushort* __restrict__ A,      // [M,K] bf16 bits
    const ushort* __restrict__ B,      // [N,K] bf16 bits
    const float*  __restrict__ scales, // [N]
    const float*  __restrict__ bias,   // [N]
    float* __restrict__ C)             // [M,N]
{
    __shared__ __align__(16) ushort As[BM * BK];  // 16 KiB
    __shared__ __align__(16) ushort Bs[BN * BK];  // 16 KiB

    const int tid  = threadIdx.x;
    const int bm   = blockIdx.y;
    const int bn   = blockIdx.x;
    const int lane = tid & 63;
    const int wave = tid >> 6;           // 0..7
    const int wm   = (wave >> 2) * 64;   // 0 or 64
    const int wn   = (wave & 3) * 32;    // 0,32,64,96
    const int l16  = lane & 15;
    const int quad = lane >> 4;
    const int swz  = l16 & 7;

    // Staging: 512 thr x 16B = 8 KiB/instr; 2 instrs per 16 KiB tile.
    // thread t -> LDS slot (row = t>>3 (+64), cg_phys = t&7); global col group
    // cg_log = cg_phys ^ (row&7). LDS byte addr = 16*t (+8192): linear in tid.
    const int srow = tid >> 3;           // 0..63
    const int cgp  = tid & 7;
    const int cgl  = cgp ^ (srow & 7);   // (srow+64)&7 == srow&7

    const ushort* ga0 = A + (size_t)(bm * BM + srow)      * K_DIM + cgl * 8;
    const ushort* ga1 = A + (size_t)(bm * BM + 64 + srow) * K_DIM + cgl * 8;
    const ushort* gb0 = B + (size_t)(bn * BN + srow)      * K_DIM + cgl * 8;
    const ushort* gb1 = B + (size_t)(bn * BN + 64 + srow) * K_DIM + cgl * 8;
    ushort* la0 = As + srow * BK + cgp * 8;
    ushort* la1 = As + (64 + srow) * BK + cgp * 8;
    ushort* lb0 = Bs + srow * BK + cgp * 8;
    ushort* lb1 = Bs + (64 + srow) * BK + cgp * 8;

    f32x4 acc[4][2] = {};

    for (int k0 = 0; k0 < K_DIM; k0 += BK) {
        __syncthreads();               // prev compute done before overwrite
        load_lds16(ga0 + k0, la0);
        load_lds16(ga1 + k0, la1);
        load_lds16(gb0 + k0, lb0);
        load_lds16(gb1 + k0, lb1);
        __syncthreads();               // drains vmcnt for lds-DMA

#pragma unroll
        for (int h = 0; h < 2; h++) {
            const int cp = (h * 4 + quad) ^ swz;   // physical col group to read
            short8 af[4], bfr[2];
#pragma unroll
            for (int i = 0; i < 4; i++)
                af[i] = *(const short8*)(As + (wm + i * 16 + l16) * BK + cp * 8);
#pragma unroll
            for (int j = 0; j < 2; j++)
                bfr[j] = *(const short8*)(Bs + (wn + j * 16 + l16) * BK + cp * 8);
#pragma unroll
            for (int i = 0; i < 4; i++)
#pragma unroll
                for (int j = 0; j < 2; j++)
                    acc[i][j] = __builtin_amdgcn_mfma_f32_16x16x32_bf16(
                        __builtin_bit_cast(bf16x8, af[i]),
                        __builtin_bit_cast(bf16x8, bfr[j]),
                        acc[i][j], 0, 0, 0);
        }
    }

    // Epilogue. C/D layout (verified m89): col = lane&15, row = quad*4 + reg.
#pragma unroll
    for (int j = 0; j < 2; j++) {
        const int col = bn * BN + wn + j * 16 + l16;
        const float s = scales[col];
        const float b = bias[col];
#pragma unroll
        for (int i = 0; i < 4; i++) {
            const int row0 = bm * BM + wm + i * 16 + quad * 4;
#pragma unroll
            for (int r = 0; r < 4; r++) {
                C[(size_t)(row0 + r) * N_DIM + col] = acc[i][j][r] * s + b;
            }
        }
    }
}

// ---------- launch ----------

extern "C" void kernel_launch(void* const* d_in, const int* in_sizes, int n_in,
                              void* d_out, int out_size, void* d_ws, size_t ws_size,
                              hipStream_t stream) {
    const float* x      = (const float*)d_in[0];   // [2,1024,4096] fp32
    const int*   w      = (const int*)d_in[1];     // [4096,4096] int, values in [-128,127]
    const float* scales = (const float*)d_in[2];   // [4096]
    const float* bias   = (const float*)d_in[3];   // [4096]
    float*       out    = (float*)d_out;           // [2,1024,4096] fp32

    ushort* Abf = (ushort*)d_ws;                                      // 16 MiB
    ushort* Bbf = (ushort*)((char*)d_ws + (size_t)M_DIM * K_DIM * 2); // 32 MiB

    cvt_fused<<<(int)(XBLK + WBLK), 256, 0, stream>>>(x, w, Abf, Bbf);

    dim3 grid(N_DIM / BN, M_DIM / BM);  // (32, 16) = 512 blocks
    gemm_bt_bf16<<<grid, 512, 0, stream>>>(Abf, Bbf, scales, bias, out);
}